// Round 4
// baseline (192.492 us; speedup 1.0000x reference)
//
#include <hip/hip_runtime.h>
#include <hip/hip_bf16.h>

#ifndef __has_builtin
#define __has_builtin(x) 0
#endif

__device__ __forceinline__ float fast_exp2(float x) {
#if __has_builtin(__builtin_amdgcn_exp2f)
  return __builtin_amdgcn_exp2f(x);
#else
  return __exp2f(x);
#endif
}
__device__ __forceinline__ float fast_rcp(float x) {
#if __has_builtin(__builtin_amdgcn_rcpf)
  return __builtin_amdgcn_rcpf(x);
#else
  return 1.0f / x;
#endif
}

#define B_   16
#define NQ_  256
#define NK_  256
#define D_   256
#define QT   4
// tanh(x) = 1 - 2/(1 + exp2(x * 2*log2(e)))
// Split-exp: exp2(s*(hq+hk)) = Eq * Ek with Eq=exp2(s*hq), Ek=exp2(s*hk).
#define TANH_SCALE 2.8853900817779268f
#define LOG2E      1.4426950408889634f
#define NEG2LOG2E  (-2.8853900817779268f)   // p = exp(-2*acc) = exp2(acc*this)

// ---------------- projection GEMM (f32 vector ALU; no f32 MFMA on CDNA4) ----
__global__ __launch_bounds__(256) void proj_kernel(
    const float* __restrict__ queries, const float* __restrict__ keys,
    const float* __restrict__ Wq, const float* __restrict__ Wk,
    const float* __restrict__ b1,
    float* __restrict__ eqs, float* __restrict__ eks)
{
  const int z = blockIdx.z;
  const float* __restrict__ X = z ? keys : queries;
  const float* __restrict__ W = z ? Wk : Wq;
  float* __restrict__ O = z ? eks : eqs;

  const int m0 = blockIdx.x * 64;
  const int n0 = blockIdx.y * 64;
  const int t  = threadIdx.x;
  const int tx = t & 15, ty = t >> 4;

  __shared__ float As_t[64][68];
  __shared__ float Bs[64][68];

  float acc[4][4] = {};

  for (int kt = 0; kt < 4; ++kt) {
    const int k0 = kt * 64;
    #pragma unroll
    for (int i = 0; i < 4; ++i) {
      int f = t + 256 * i;
      int row = f >> 4;
      int kc  = (f & 15) << 2;
      float4 v = *(const float4*)&X[(size_t)(m0 + row) * D_ + (k0 + kc)];
      As_t[kc + 0][row] = v.x; As_t[kc + 1][row] = v.y;
      As_t[kc + 2][row] = v.z; As_t[kc + 3][row] = v.w;
    }
    #pragma unroll
    for (int i = 0; i < 4; ++i) {
      int f = t + 256 * i;
      int kr = f >> 4;
      int nc = (f & 15) << 2;
      *(float4*)&Bs[kr][nc] = *(const float4*)&W[(size_t)(k0 + kr) * D_ + (n0 + nc)];
    }
    __syncthreads();
    #pragma unroll 8
    for (int k = 0; k < 64; ++k) {
      float4 a = *(const float4*)&As_t[k][ty << 2];
      float4 b = *(const float4*)&Bs[k][tx << 2];
      float aa[4] = {a.x, a.y, a.z, a.w};
      float bb[4] = {b.x, b.y, b.z, b.w};
      #pragma unroll
      for (int i = 0; i < 4; ++i)
        #pragma unroll
        for (int j = 0; j < 4; ++j)
          acc[i][j] = fmaf(aa[i], bb[j], acc[i][j]);
    }
    __syncthreads();
  }

  float bias[4] = {0.f, 0.f, 0.f, 0.f};
  if (z == 0) {
    #pragma unroll
    for (int j = 0; j < 4; ++j) bias[j] = b1[n0 + (tx << 2) + j];
  }
  #pragma unroll
  for (int i = 0; i < 4; ++i)
    #pragma unroll
    for (int j = 0; j < 4; ++j)
      O[(size_t)(m0 + (ty << 2) + i) * D_ + n0 + (tx << 2) + j] =
          fast_exp2(TANH_SCALE * (acc[i][j] + bias[j]));
}

// ---------------- key-split flash attention (no-max softmax) ---------------
// Grid 2048 = kh(2) x qq(64) x b(16); wgid = kh*1024 + qq*16 + b.
// Block: 128 keys [kh*128, kh*128+128), QT=4 queries, 256 threads.
// Thread t: key = kh*128 + (t&127), d-half kdh = t>>7 (wave-uniform -> eq/w2
// stay scalar loads). Partial logits combined via 4KB LDS exchange.
// No max pass: |logit| <= 2*sum|w2| ~ 26, exp2 range safe in f32.
// Paired rcp: w0/t0 + w1/t1 = (w0*t1 + w1*t0)*rcp(t0*t1)  (t >= 1 always).
// Outputs per block: sctx[wgid][4][256] (unnormalized ctx), psum[wgid][2][4].
__global__ __launch_bounds__(256, 8) void attn_split(
    const float* __restrict__ eqs, const float* __restrict__ eks,
    const float* __restrict__ values, const float* __restrict__ w2,
    float* __restrict__ sctx, float* __restrict__ psum)
{
  const int wgid = blockIdx.x;
  const int b    = wgid & 15;
  const int qq   = (wgid >> 4) & 63;
  const int kh   = wgid >> 10;
  const int q0   = qq * QT;
  const int t    = threadIdx.x;
  const int lane = t & 63, wave = t >> 6;
  const int kloc = t & 127;
  const int kdh  = t >> 7;

  // pvred (16KB) overlays plog (4KB) — disjoint lifetimes, barrier between.
  __shared__ __align__(16) char smem[4 * 4 * 256 * 4];
  float (*plog)[128][4]  = (float(*)[128][4])smem;   // [2][128][4]
  float (*pvred)[4][256] = (float(*)[4][256])smem;   // [4][4][256]

  // ---- partial logits over this thread's d-half ----
  const float* __restrict__ ekrow =
      eks + ((size_t)(b * NK_) + kh * 128 + kloc) * D_ + kdh * 128;
  const float* __restrict__ equ =
      eqs + ((size_t)(b * NQ_) + q0) * D_ + kdh * 128;   // uniform
  const float* __restrict__ w2u = w2 + kdh * 128;        // uniform

  float acc[QT] = {};
  #pragma unroll 4
  for (int d4 = 0; d4 < 32; ++d4) {
    float4 ekv = *(const float4*)&ekrow[d4 << 2];
    float4 wv  = *(const float4*)&w2u[d4 << 2];
    #pragma unroll
    for (int qi = 0; qi < QT; ++qi) {
      float4 eqv = *(const float4*)&equ[(size_t)qi * D_ + (d4 << 2)];
      float t0 = fmaf(eqv.x, ekv.x, 1.0f);
      float t1 = fmaf(eqv.y, ekv.y, 1.0f);
      float n01 = wv.x * t1;  n01 = fmaf(wv.y, t0, n01);
      float r01 = fast_rcp(t0 * t1);
      acc[qi] = fmaf(n01, r01, acc[qi]);
      float t2 = fmaf(eqv.z, ekv.z, 1.0f);
      float t3 = fmaf(eqv.w, ekv.w, 1.0f);
      float n23 = wv.z * t3;  n23 = fmaf(wv.w, t2, n23);
      float r23 = fast_rcp(t2 * t3);
      acc[qi] = fmaf(n23, r23, acc[qi]);
    }
  }

  // ---- exchange d-half partials, compute unnormalized p ----
  {
    float4 a4; a4.x = acc[0]; a4.y = acc[1]; a4.z = acc[2]; a4.w = acc[3];
    *(float4*)&plog[kdh][kloc][0] = a4;
  }
  __syncthreads();
  float p[QT];
  {
    float4 o4 = *(const float4*)&plog[1 - kdh][kloc][0];
    float other[4] = {o4.x, o4.y, o4.z, o4.w};
    #pragma unroll
    for (int qi = 0; qi < QT; ++qi)
      p[qi] = fast_exp2(NEG2LOG2E * (acc[qi] + other[qi]));
  }

  // ---- partial softmax denominator (kdh==0 waves hold all 128 keys) ----
  if (kdh == 0) {
    #pragma unroll
    for (int qi = 0; qi < QT; ++qi) {
      float v = p[qi];
      #pragma unroll
      for (int off = 32; off; off >>= 1) v += __shfl_xor(v, off, 64);
      if (lane == 0) psum[(size_t)wgid * 8 + wave * 4 + qi] = v;
    }
  }
  __syncthreads();   // protects plog before pvred overwrite

  // ---- PV: each wave 32 keys (p broadcast via readlane from own lanes) ----
  const int src_base = (wave >> 1) * 32;            // readlane base
  const int key_base = (wave & 1) * 64 + src_base;  // local key base
  float ctx[QT][4] = {};
  const float* __restrict__ vbase =
      values + ((size_t)(b * NK_) + kh * 128 + key_base) * D_ + (lane << 2);
  #pragma unroll 4
  for (int i = 0; i < 32; ++i) {
    float4 vv = *(const float4*)&vbase[(size_t)i * D_];
    float vz[4] = {vv.x, vv.y, vv.z, vv.w};
    #pragma unroll
    for (int qi = 0; qi < QT; ++qi) {
      float pk = __int_as_float(
          __builtin_amdgcn_readlane(__float_as_int(p[qi]), src_base + i));
      #pragma unroll
      for (int j = 0; j < 4; ++j)
        ctx[qi][j] = fmaf(pk, vz[j], ctx[qi][j]);
    }
  }

  // ---- combine 4 waves, write partial ctx ----
  #pragma unroll
  for (int qi = 0; qi < QT; ++qi) {
    float4 v4; v4.x = ctx[qi][0]; v4.y = ctx[qi][1];
    v4.z = ctx[qi][2]; v4.w = ctx[qi][3];
    *(float4*)&pvred[wave][qi][lane << 2] = v4;
  }
  __syncthreads();
  #pragma unroll
  for (int qi = 0; qi < QT; ++qi) {
    float s = pvred[0][qi][t] + pvred[1][qi][t] +
              pvred[2][qi][t] + pvred[3][qi][t];
    sctx[((size_t)wgid * 4 + qi) * 256 + t] = s;
  }
}

// ---------------- combine the two key-halves --------------------------------
__global__ __launch_bounds__(256) void combine_kernel(
    const float* __restrict__ sctx, const float* __restrict__ psum,
    float* __restrict__ out)
{
  const int bid = blockIdx.x;     // 1024 = qq*16 + b
  const int b = bid & 15, qq = bid >> 4;
  const int t = threadIdx.x;
  const size_t blk0 = bid, blk1 = bid + 1024;

  float s[QT];
  #pragma unroll
  for (int qi = 0; qi < QT; ++qi)
    s[qi] = psum[blk0 * 8 + qi] + psum[blk0 * 8 + 4 + qi] +
            psum[blk1 * 8 + qi] + psum[blk1 * 8 + 4 + qi];

  #pragma unroll
  for (int qi = 0; qi < QT; ++qi) {
    float v = sctx[(blk0 * 4 + qi) * 256 + t] + sctx[(blk1 * 4 + qi) * 256 + t];
    out[((size_t)(b * NQ_) + qq * QT + qi) * D_ + t] = v * fast_rcp(s[qi]);
  }
}

// ---------------- fallback (R3 kernel, verbatim): used if ws too small ------
__global__ __launch_bounds__(256, 4) void attn_fallback(
    const float* __restrict__ eqs, const float* __restrict__ eks,
    const float* __restrict__ values, const float* __restrict__ w2,
    float* __restrict__ out)
{
  const int wgid = blockIdx.x;
  const int b  = wgid & 15;
  const int q0 = (wgid >> 4) * QT;
  const int t  = threadIdx.x;
  const int lane = t & 63, wave = t >> 6;

  __shared__ float pvred[4][QT][D_];
  __shared__ float redA[4][QT], redB[4][QT];

  const float* __restrict__ ekrow = eks + ((size_t)(b * NK_) + t) * D_;
  const float* __restrict__ equni = eqs + ((size_t)(b * NQ_) + q0) * D_;
  float acc[QT] = {};
  #pragma unroll 4
  for (int d4 = 0; d4 < D_ / 4; ++d4) {
    float4 ekv = *(const float4*)&ekrow[d4 << 2];
    float4 wv  = *(const float4*)&w2[d4 << 2];
    float e[4] = {ekv.x, ekv.y, ekv.z, ekv.w};
    float w[4] = {wv.x, wv.y, wv.z, wv.w};
    #pragma unroll
    for (int qi = 0; qi < QT; ++qi) {
      float4 eqv = *(const float4*)&equni[(size_t)qi * D_ + (d4 << 2)];
      float a[4] = {eqv.x, eqv.y, eqv.z, eqv.w};
      #pragma unroll
      for (int j = 0; j < 4; ++j) {
        float t0 = fmaf(a[j], e[j], 1.0f);
        acc[qi] = fmaf(w[j], fast_rcp(t0), acc[qi]);
      }
    }
  }

  float logit[QT];
  #pragma unroll
  for (int qi = 0; qi < QT; ++qi) logit[qi] = -2.0f * acc[qi];

  #pragma unroll
  for (int qi = 0; qi < QT; ++qi) {
    float v = logit[qi];
    #pragma unroll
    for (int off = 32; off; off >>= 1) v = fmaxf(v, __shfl_xor(v, off, 64));
    if (lane == 0) redA[wave][qi] = v;
  }
  __syncthreads();
  float mx[QT];
  #pragma unroll
  for (int qi = 0; qi < QT; ++qi)
    mx[qi] = fmaxf(fmaxf(redA[0][qi], redA[1][qi]),
                   fmaxf(redA[2][qi], redA[3][qi]));

  float p[QT];
  #pragma unroll
  for (int qi = 0; qi < QT; ++qi)
    p[qi] = fast_exp2((logit[qi] - mx[qi]) * LOG2E);
  #pragma unroll
  for (int qi = 0; qi < QT; ++qi) {
    float v = p[qi];
    #pragma unroll
    for (int off = 32; off; off >>= 1) v += __shfl_xor(v, off, 64);
    if (lane == 0) redB[wave][qi] = v;
  }
  __syncthreads();
  float pl[QT];
  #pragma unroll
  for (int qi = 0; qi < QT; ++qi) {
    float inv = fast_rcp(redB[0][qi] + redB[1][qi] + redB[2][qi] + redB[3][qi]);
    pl[qi] = p[qi] * inv;
  }

  float ctx[QT][4] = {};
  const float* __restrict__ vbase =
      values + ((size_t)(b * NK_) + (wave << 6)) * D_ + (lane << 2);
  #pragma unroll 4
  for (int kl = 0; kl < 64; ++kl) {
    float4 vv = *(const float4*)&vbase[(size_t)kl * D_];
    float vz[4] = {vv.x, vv.y, vv.z, vv.w};
    #pragma unroll
    for (int qi = 0; qi < QT; ++qi) {
      float pk = __int_as_float(
          __builtin_amdgcn_readlane(__float_as_int(pl[qi]), kl));
      #pragma unroll
      for (int j = 0; j < 4; ++j)
        ctx[qi][j] = fmaf(pk, vz[j], ctx[qi][j]);
    }
  }

  #pragma unroll
  for (int qi = 0; qi < QT; ++qi) {
    float4 v4; v4.x = ctx[qi][0]; v4.y = ctx[qi][1];
    v4.z = ctx[qi][2]; v4.w = ctx[qi][3];
    *(float4*)&pvred[wave][qi][lane << 2] = v4;
  }
  __syncthreads();
  #pragma unroll
  for (int qi = 0; qi < QT; ++qi) {
    float o = pvred[0][qi][t] + pvred[1][qi][t] +
              pvred[2][qi][t] + pvred[3][qi][t];
    out[((size_t)(b * NQ_) + q0 + qi) * D_ + t] = o;
  }
}

extern "C" void kernel_launch(void* const* d_in, const int* in_sizes, int n_in,
                              void* d_out, int out_size, void* d_ws, size_t ws_size,
                              hipStream_t stream)
{
  const float* keys    = (const float*)d_in[0];
  const float* queries = (const float*)d_in[1];
  const float* values  = (const float*)d_in[2];
  const float* Wk      = (const float*)d_in[3];
  const float* Wq      = (const float*)d_in[4];
  const float* b1      = (const float*)d_in[5];
  const float* w2      = (const float*)d_in[6];
  // d_in[7] = b2: dropped (softmax shift-invariance)

  float* eqs  = (float*)d_ws;                      // [4096,256] f32, 4 MB
  float* eks  = eqs + (size_t)B_ * NQ_ * D_;       // [4096,256] f32, 4 MB
  float* sctx = eks + (size_t)B_ * NK_ * D_;       // [2048][4][256] f32, 8 MB
  float* psum = sctx + (size_t)2048 * 4 * 256;     // [2048][2][4] f32, 64 KB
  float* out  = (float*)d_out;

  const size_t need = ((size_t)2 * B_ * NQ_ * D_ + (size_t)2048 * 4 * 256 +
                       (size_t)2048 * 8) * sizeof(float);   // ~16.1 MB

  dim3 pgrid(B_ * NQ_ / 64, D_ / 64, 2);
  proj_kernel<<<pgrid, 256, 0, stream>>>(queries, keys, Wq, Wk, b1, eqs, eks);

  if (ws_size >= need) {
    attn_split<<<dim3(2048), 256, 0, stream>>>(eqs, eks, values, w2, sctx, psum);
    combine_kernel<<<dim3(1024), 256, 0, stream>>>(sctx, psum, out);
  } else {
    attn_fallback<<<dim3(B_ * NQ_ / QT), 256, 0, stream>>>(eqs, eks, values, w2, out);
  }
}

// Round 5
// 75.436 us; speedup vs baseline: 2.5517x; 2.5517x over previous
//
#include <hip/hip_runtime.h>
#include <hip/hip_bf16.h>

#ifndef __has_builtin
#define __has_builtin(x) 0
#endif

typedef float v2f __attribute__((ext_vector_type(2)));

__device__ __forceinline__ float fast_exp2(float x) {
#if __has_builtin(__builtin_amdgcn_exp2f)
  return __builtin_amdgcn_exp2f(x);
#else
  return __exp2f(x);
#endif
}
__device__ __forceinline__ float fast_rcp(float x) {
#if __has_builtin(__builtin_amdgcn_rcpf)
  return __builtin_amdgcn_rcpf(x);
#else
  return 1.0f / x;
#endif
}
// v_pk_fma_f32: 2 FMAs per 2-cycle wave instr (f32 peak only reachable packed)
__device__ __forceinline__ v2f pk_fma(v2f a, v2f b, v2f c) {
#if __has_builtin(__builtin_elementwise_fma)
  return __builtin_elementwise_fma(a, b, c);
#else
  v2f r; r.x = fmaf(a.x, b.x, c.x); r.y = fmaf(a.y, b.y, c.y); return r;
#endif
}

#define B_   16
#define NQ_  256
#define NK_  256
#define D_   256
#define QT   4
// tanh(x) = 1 - 2/(1 + exp2(x * 2*log2(e)))
// Split-exp: exp2(s*(hq+hk)) = Eq * Ek with Eq=exp2(s*hq), Ek=exp2(s*hk).
#define TANH_SCALE 2.8853900817779268f
#define LOG2E      1.4426950408889634f

// ---------------- projection GEMM (packed f32 vector ALU) ------------------
// z=0: Eq = exp2(TANH_SCALE*(queries@Wq + b1))   [4096,256]
// z=1: Ek = exp2(TANH_SCALE*(keys@Wk))           [4096,256]
__global__ __launch_bounds__(256) void proj_kernel(
    const float* __restrict__ queries, const float* __restrict__ keys,
    const float* __restrict__ Wq, const float* __restrict__ Wk,
    const float* __restrict__ b1,
    float* __restrict__ eqs, float* __restrict__ eks)
{
  const int z = blockIdx.z;
  const float* __restrict__ X = z ? keys : queries;
  const float* __restrict__ W = z ? Wk : Wq;
  float* __restrict__ O = z ? eks : eqs;

  const int m0 = blockIdx.x * 64;
  const int n0 = blockIdx.y * 64;
  const int t  = threadIdx.x;
  const int tx = t & 15, ty = t >> 4;

  __shared__ float As_t[64][68];
  __shared__ float Bs[64][68];

  v2f acc2[4][2] = {};   // [i][j-pair]

  for (int kt = 0; kt < 4; ++kt) {
    const int k0 = kt * 64;
    #pragma unroll
    for (int i = 0; i < 4; ++i) {          // A tile, stored transposed
      int f = t + 256 * i;
      int row = f >> 4;
      int kc  = (f & 15) << 2;
      float4 v = *(const float4*)&X[(size_t)(m0 + row) * D_ + (k0 + kc)];
      As_t[kc + 0][row] = v.x; As_t[kc + 1][row] = v.y;
      As_t[kc + 2][row] = v.z; As_t[kc + 3][row] = v.w;
    }
    #pragma unroll
    for (int i = 0; i < 4; ++i) {          // B tile
      int f = t + 256 * i;
      int kr = f >> 4;
      int nc = (f & 15) << 2;
      *(float4*)&Bs[kr][nc] = *(const float4*)&W[(size_t)(k0 + kr) * D_ + (n0 + nc)];
    }
    __syncthreads();
    #pragma unroll 8
    for (int k = 0; k < 64; ++k) {
      float4 a = *(const float4*)&As_t[k][ty << 2];
      float4 b = *(const float4*)&Bs[k][tx << 2];
      v2f b01; b01.x = b.x; b01.y = b.y;
      v2f b23; b23.x = b.z; b23.y = b.w;
      float aa[4] = {a.x, a.y, a.z, a.w};
      #pragma unroll
      for (int i = 0; i < 4; ++i) {
        v2f ai; ai.x = aa[i]; ai.y = aa[i];
        acc2[i][0] = pk_fma(ai, b01, acc2[i][0]);
        acc2[i][1] = pk_fma(ai, b23, acc2[i][1]);
      }
    }
    __syncthreads();
  }

  float bias[4] = {0.f, 0.f, 0.f, 0.f};
  if (z == 0) {
    #pragma unroll
    for (int j = 0; j < 4; ++j) bias[j] = b1[n0 + (tx << 2) + j];
  }
  #pragma unroll
  for (int i = 0; i < 4; ++i) {
    float av[4] = {acc2[i][0].x, acc2[i][0].y, acc2[i][1].x, acc2[i][1].y};
    #pragma unroll
    for (int j = 0; j < 4; ++j)
      O[(size_t)(m0 + (ty << 2) + i) * D_ + n0 + (tx << 2) + j] =
          fast_exp2(TANH_SCALE * (av[j] + bias[j]));
  }
}

// ---------------- fused logits + softmax + PV ------------------------------
// Block = (b, 4 queries), 256 threads. Thread t = key t in logits.
// logit_eff = -2 * sum_d w2[d] * rcp(1 + Eq[d]*Ek[d])   (consts dropped)
// eq/w2 staged in LDS (5KB), read as conflict-free float4 BROADCASTS
// (in-order DS returns -> fine-grained lgkmcnt, unlike s_load's lgkmcnt(0)).
// Paired rcp: w0/t0 + w1/t1 = (w0*t1 + w1*t0) * rcp(t0*t1); t in [~0,5e5]
// so the product never overflows. pk_fma for the t-pair computation.
// PV: wave w owns keys 64w..63+64w, p broadcast via readlane; 16KB LDS pass.
// b = wgid&15 pins 2 batches per XCD (round-robin dispatch) -> L2-resident.
__global__ __launch_bounds__(256, 4) void attn_kernel(
    const float* __restrict__ eqs, const float* __restrict__ eks,
    const float* __restrict__ values, const float* __restrict__ w2,
    float* __restrict__ out)
{
  const int wgid = blockIdx.x;
  const int b  = wgid & 15;
  const int q0 = (wgid >> 4) * QT;
  const int t  = threadIdx.x;
  const int lane = t & 63, wave = t >> 6;

  __shared__ float eqw[QT + 1][D_];        // [0..3]=Eq rows, [4]=w2 (5KB)
  __shared__ float pvred[4][QT][D_];       // 16KB
  __shared__ float redA[4][QT], redB[4][QT];

  #pragma unroll
  for (int qi = 0; qi < QT; ++qi)
    eqw[qi][t] = eqs[((size_t)(b * NQ_) + q0 + qi) * D_ + t];
  eqw[QT][t] = w2[t];
  __syncthreads();

  // ---- logits ----
  const float* __restrict__ ekrow = eks + ((size_t)(b * NK_) + t) * D_;
  float acc[QT] = {};
  float4 ekn = *(const float4*)&ekrow[0];
  #pragma unroll 4
  for (int d4 = 0; d4 < D_ / 4; ++d4) {
    float4 ekv = ekn;
    if (d4 < D_ / 4 - 1) ekn = *(const float4*)&ekrow[(d4 + 1) << 2];
    float4 wv = *(const float4*)&eqw[QT][d4 << 2];        // LDS broadcast
    v2f ek01; ek01.x = ekv.x; ek01.y = ekv.y;
    v2f ek23; ek23.x = ekv.z; ek23.y = ekv.w;
    v2f one; one.x = 1.0f; one.y = 1.0f;
    #pragma unroll
    for (int qi = 0; qi < QT; ++qi) {
      float4 eqv = *(const float4*)&eqw[qi][d4 << 2];     // LDS broadcast
      v2f eq01; eq01.x = eqv.x; eq01.y = eqv.y;
      v2f eq23; eq23.x = eqv.z; eq23.y = eqv.w;
      v2f t01 = pk_fma(eq01, ek01, one);
      float n01 = fmaf(wv.y, t01.x, wv.x * t01.y);
      acc[qi] = fmaf(n01, fast_rcp(t01.x * t01.y), acc[qi]);
      v2f t23 = pk_fma(eq23, ek23, one);
      float n23 = fmaf(wv.w, t23.x, wv.z * t23.y);
      acc[qi] = fmaf(n23, fast_rcp(t23.x * t23.y), acc[qi]);
    }
  }

  float logit[QT];
  #pragma unroll
  for (int qi = 0; qi < QT; ++qi) logit[qi] = -2.0f * acc[qi];

  // ---- softmax over keys (block-wide) ----
  #pragma unroll
  for (int qi = 0; qi < QT; ++qi) {
    float v = logit[qi];
    #pragma unroll
    for (int off = 32; off; off >>= 1) v = fmaxf(v, __shfl_xor(v, off, 64));
    if (lane == 0) redA[wave][qi] = v;
  }
  __syncthreads();
  float mx[QT];
  #pragma unroll
  for (int qi = 0; qi < QT; ++qi)
    mx[qi] = fmaxf(fmaxf(redA[0][qi], redA[1][qi]),
                   fmaxf(redA[2][qi], redA[3][qi]));

  float p[QT];
  #pragma unroll
  for (int qi = 0; qi < QT; ++qi)
    p[qi] = fast_exp2((logit[qi] - mx[qi]) * LOG2E);
  #pragma unroll
  for (int qi = 0; qi < QT; ++qi) {
    float v = p[qi];
    #pragma unroll
    for (int off = 32; off; off >>= 1) v += __shfl_xor(v, off, 64);
    if (lane == 0) redB[wave][qi] = v;
  }
  __syncthreads();
  float pl[QT];
  #pragma unroll
  for (int qi = 0; qi < QT; ++qi) {
    float inv = fast_rcp(redB[0][qi] + redB[1][qi] + redB[2][qi] + redB[3][qi]);
    pl[qi] = p[qi] * inv;   // normalized weight for this thread's key
  }

  // ---- PV: wave-local over its 64 keys, p broadcast via readlane ----
  float ctx[QT][4] = {};
  const float* __restrict__ vbase =
      values + ((size_t)(b * NK_) + (wave << 6)) * D_ + (lane << 2);
  #pragma unroll 4
  for (int kl = 0; kl < 64; ++kl) {
    float4 vv = *(const float4*)&vbase[(size_t)kl * D_];
    float vz[4] = {vv.x, vv.y, vv.z, vv.w};
    #pragma unroll
    for (int qi = 0; qi < QT; ++qi) {
      float pk = __int_as_float(
          __builtin_amdgcn_readlane(__float_as_int(pl[qi]), kl));
      #pragma unroll
      for (int j = 0; j < 4; ++j)
        ctx[qi][j] = fmaf(pk, vz[j], ctx[qi][j]);
    }
  }

  // ---- combine 4 waves' partials via LDS ----
  #pragma unroll
  for (int qi = 0; qi < QT; ++qi) {
    float4 v4; v4.x = ctx[qi][0]; v4.y = ctx[qi][1];
    v4.z = ctx[qi][2]; v4.w = ctx[qi][3];
    *(float4*)&pvred[wave][qi][lane << 2] = v4;
  }
  __syncthreads();
  #pragma unroll
  for (int qi = 0; qi < QT; ++qi) {
    float o = pvred[0][qi][t] + pvred[1][qi][t] +
              pvred[2][qi][t] + pvred[3][qi][t];
    out[((size_t)(b * NQ_) + q0 + qi) * D_ + t] = o;
  }
}

extern "C" void kernel_launch(void* const* d_in, const int* in_sizes, int n_in,
                              void* d_out, int out_size, void* d_ws, size_t ws_size,
                              hipStream_t stream)
{
  const float* keys    = (const float*)d_in[0];
  const float* queries = (const float*)d_in[1];
  const float* values  = (const float*)d_in[2];
  const float* Wk      = (const float*)d_in[3];
  const float* Wq      = (const float*)d_in[4];
  const float* b1      = (const float*)d_in[5];
  const float* w2      = (const float*)d_in[6];
  // d_in[7] = b2: dropped (softmax shift-invariance)

  float* eqs = (float*)d_ws;                       // [4096,256] f32, 4 MB
  float* eks = eqs + (size_t)B_ * NQ_ * D_;        // [4096,256] f32, 4 MB
  float* out = (float*)d_out;

  dim3 pgrid(B_ * NQ_ / 64, D_ / 64, 2);           // 64 x 4 x 2 = 512 blocks
  proj_kernel<<<pgrid, 256, 0, stream>>>(queries, keys, Wq, Wk, b1, eqs, eks);

  attn_kernel<<<dim3(B_ * NQ_ / QT), 256, 0, stream>>>(eqs, eks, values, w2, out);
}